// Round 5
// baseline (674.236 us; speedup 1.0000x reference)
//
#include <hip/hip_runtime.h>
#include <math.h>

// ---------------------------------------------------------------------------
// Graph attention (per-dst softmax) + weighted segment_max aggregation +
// gated update + per-graph sum readout + linear classifier.
//
// Pipeline (all on `stream`):
//   0. memset deg/cursor/hg = 0
//   1. k_ps_pd   : ps = H @ Wa[:D], pd = H @ Wa[D:]           (wave/node, f4)
//   2. k_hist    : deg[dst]++                                  (edge-parallel)
//   3. k_scan1/2/3: offs = exclusive_scan(deg)   (CSR offsets)
//   4. k_scatter : ssrc[offs[dst]+rank] = src    (dst-sorted edge list)
//   5. k_fused   : per wave: KNODES consecutive dst nodes; per node:
//                  lane-parallel softmax over incoming edges (shfl bcast),
//                  acc = max_e a_e*H[src_e] (float4 gathers, 2x unrolled),
//                  gated update, register graph sum, atomic flush per run
//   6. k_out     : out[b,c] = lrelu(hg[b,:]) @ Wl[:,c] + bl[c] (lane/class)
// ---------------------------------------------------------------------------

#define SLOPE 0.01f
#define KNODES 8   // nodes per wave; 8 keeps ~2.3 waves/slot of TLP at N=150k

__device__ __forceinline__ float lrelu(float x) { return x >= 0.f ? x : SLOPE * x; }

__device__ __forceinline__ float wrsum(float v) {
#pragma unroll
    for (int m = 32; m >= 1; m >>= 1) v += __shfl_xor(v, m, 64);
    return v;
}
__device__ __forceinline__ float wrmax(float v) {
#pragma unroll
    for (int m = 32; m >= 1; m >>= 1) v = fmaxf(v, __shfl_xor(v, m, 64));
    return v;
}

// ---- 1. per-node attention projections (float4) ---------------------------
__global__ __launch_bounds__(256) void k_ps_pd(
    const float* __restrict__ H, const float* __restrict__ Wa,
    float* __restrict__ ps, float* __restrict__ pd, int N, int D) {
    int wid  = (blockIdx.x * blockDim.x + threadIdx.x) >> 6;
    int lane = threadIdx.x & 63;
    if (wid >= N) return;
    const float4* row = (const float4*)(H + (size_t)wid * D);
    const float4* wa0 = (const float4*)Wa;
    const float4* wa1 = (const float4*)(Wa + D);   // D%4==0 -> 16B aligned
    int nv = D >> 2;
    float s0 = 0.f, s1 = 0.f;
    for (int v = lane; v < nv; v += 64) {
        float4 h = row[v], a = wa0[v], b = wa1[v];
        s0 += h.x * a.x + h.y * a.y + h.z * a.z + h.w * a.w;
        s1 += h.x * b.x + h.y * b.y + h.z * b.z + h.w * b.w;
    }
    s0 = wrsum(s0);
    s1 = wrsum(s1);
    if (lane == 0) { ps[wid] = s0; pd[wid] = s1; }
}

// ---- 2. in-degree histogram ----------------------------------------------
__global__ __launch_bounds__(256) void k_hist(
    const int* __restrict__ dst, unsigned* __restrict__ deg, int E) {
    int e = blockIdx.x * blockDim.x + threadIdx.x;
    if (e < E) atomicAdd(&deg[dst[e]], 1u);
}

// ---- 3. exclusive scan (3 kernels, 1024-elem tiles) ----------------------
__global__ __launch_bounds__(256) void k_scan1(
    const unsigned* __restrict__ deg, unsigned* __restrict__ offs,
    unsigned* __restrict__ bsum, int N) {
    __shared__ unsigned wsum[4];
    int t = threadIdx.x, b = blockIdx.x;
    int base = b * 1024 + t * 4;
    unsigned v[4];
#pragma unroll
    for (int j = 0; j < 4; j++) { int i = base + j; v[j] = (i < N) ? deg[i] : 0u; }
    unsigned p0 = v[0], p1 = p0 + v[1], p2 = p1 + v[2], p3 = p2 + v[3];
    unsigned tot = p3;
    unsigned x = tot;
    int lane = t & 63, w = t >> 6;
#pragma unroll
    for (int d = 1; d < 64; d <<= 1) { unsigned y = __shfl_up(x, d, 64); if (lane >= d) x += y; }
    if (lane == 63) wsum[w] = x;
    __syncthreads();
    unsigned woff = 0;
    for (int i = 0; i < w; i++) woff += wsum[i];
    unsigned excl = woff + x - tot;  // exclusive prefix of this thread's 4 elems
    unsigned incl[4] = {excl + p0, excl + p1, excl + p2, excl + p3};
#pragma unroll
    for (int j = 0; j < 4; j++) { int i = base + j; if (i < N) offs[i + 1] = incl[j]; }
    if (t == 255) bsum[b] = excl + tot;  // block total
}

__global__ __launch_bounds__(256) void k_scan2(
    const unsigned* __restrict__ bsum, unsigned* __restrict__ bpre, int nT) {
    __shared__ unsigned wsum[4];
    int t = threadIdx.x;
    unsigned v[8], p[8];
    unsigned run = 0;
#pragma unroll
    for (int j = 0; j < 8; j++) { int i = t * 8 + j; v[j] = (i < nT) ? bsum[i] : 0u; run += v[j]; p[j] = run; }
    unsigned tot = run, x = tot;
    int lane = t & 63, w = t >> 6;
#pragma unroll
    for (int d = 1; d < 64; d <<= 1) { unsigned y = __shfl_up(x, d, 64); if (lane >= d) x += y; }
    if (lane == 63) wsum[w] = x;
    __syncthreads();
    unsigned woff = 0;
    for (int i = 0; i < w; i++) woff += wsum[i];
    unsigned excl = woff + x - tot;
#pragma unroll
    for (int j = 0; j < 8; j++) { int i = t * 8 + j; if (i < nT) bpre[i] = excl + (j ? p[j - 1] : 0u); }
}

__global__ __launch_bounds__(256) void k_scan3(
    unsigned* __restrict__ offs, const unsigned* __restrict__ bpre, int N) {
    int i = blockIdx.x * blockDim.x + threadIdx.x;
    if (i == 0) offs[0] = 0u;
    if (i < N) offs[i + 1] += bpre[i >> 10];
}

// ---- 4. scatter edges into dst-sorted order ------------------------------
__global__ __launch_bounds__(256) void k_scatter(
    const int* __restrict__ src, const int* __restrict__ dst,
    const unsigned* __restrict__ offs, unsigned* __restrict__ cur,
    int* __restrict__ ssrc, int E) {
    int e = blockIdx.x * blockDim.x + threadIdx.x;
    if (e >= E) return;
    int d = dst[e];
    unsigned r = atomicAdd(&cur[d], 1u);
    ssrc[offs[d] + r] = src[e];
}

// ---- 5. fused softmax + weighted segment_max + gate + graph-sum ----------
// One wave per KNODES consecutive dst nodes. Column map: lane owns float4 #lane
// and (if q1) float4 #(64+lane).  Requires D%4==0, D<=512.
__global__ __launch_bounds__(256) void k_fused(
    const float* __restrict__ H, const float* __restrict__ eta,
    const float* __restrict__ ps, const float* __restrict__ pd,
    const float* __restrict__ battn,
    const unsigned* __restrict__ offs, const int* __restrict__ ssrc,
    const int* __restrict__ gid, float* __restrict__ hg,
    int N, int D) {
    int wid  = (blockIdx.x * blockDim.x + threadIdx.x) >> 6;
    int lane = threadIdx.x & 63;
    int n0 = wid * KNODES;
    if (n0 >= N) return;
    int n1 = min(n0 + KNODES, N);
    int nv = D >> 2;
    bool q0 = lane < nv;          // first float4 valid (always for D>=256)
    bool q1 = (64 + lane) < nv;   // second float4 valid (lane < nv-64)
    float b0 = battn[0];

    // register graph-sum accumulators (2 float4)
    float sx = 0.f, sy = 0.f, sz = 0.f, sw = 0.f;
    float tx = 0.f, ty = 0.f, tz = 0.f, tw = 0.f;
    int curg = gid[n0];

    for (int n = n0; n < n1; ++n) {
        unsigned e0 = offs[n], e1 = offs[n + 1];
        int degn = (int)(e1 - e0);
        const float4* hrow = (const float4*)(H + (size_t)n * D);
        float4 h0 = {0, 0, 0, 0}, h1 = {0, 0, 0, 0};
        if (q0) h0 = hrow[lane];
        if (q1) h1 = hrow[64 + lane];
        // h_new for this node (deg==0 -> node passes through untouched)
        float hx = h0.x, hy = h0.y, hz = h0.z, hw = h0.w;
        float gx = h1.x, gy = h1.y, gz = h1.z, gw = h1.w;
        if (degn > 0) {
            float pdn = pd[n] + b0;
            float ax = -INFINITY, ay = -INFINITY, az = -INFINITY, aw = -INFINITY;
            float bx = -INFINITY, by = -INFINITY, bz = -INFINITY, bw = -INFINITY;
            if (degn <= 64) {
                // lane-parallel softmax, one edge per lane
                int   sn_l = (lane < degn) ? ssrc[e0 + lane] : 0;
                float w_l  = (lane < degn) ? lrelu(ps[sn_l] + pdn) : -INFINITY;
                float m    = wrmax(w_l);
                float ex   = (lane < degn) ? expf(w_l - m) : 0.f;
                float s    = wrsum(ex);
                float a_l  = ex * (1.f / s);
                // 2x-unrolled edge loop: two independent row gathers in
                // flight per iteration (fmax accumulation is order-free)
                int e = 0;
                for (; e + 1 < degn; e += 2) {
                    float a0s = __shfl(a_l, e, 64);
                    int   sn0 = __shfl(sn_l, e, 64);
                    float a1s = __shfl(a_l, e + 1, 64);
                    int   sn1 = __shfl(sn_l, e + 1, 64);
                    const float4* r0 = (const float4*)(H + (size_t)sn0 * D);
                    const float4* r1 = (const float4*)(H + (size_t)sn1 * D);
                    if (q0) {
                        float4 u = r0[lane];
                        float4 v = r1[lane];
                        ax = fmaxf(fmaxf(ax, a0s * u.x), a1s * v.x);
                        ay = fmaxf(fmaxf(ay, a0s * u.y), a1s * v.y);
                        az = fmaxf(fmaxf(az, a0s * u.z), a1s * v.z);
                        aw = fmaxf(fmaxf(aw, a0s * u.w), a1s * v.w);
                    }
                    if (q1) {
                        float4 u = r0[64 + lane];
                        float4 v = r1[64 + lane];
                        bx = fmaxf(fmaxf(bx, a0s * u.x), a1s * v.x);
                        by = fmaxf(fmaxf(by, a0s * u.y), a1s * v.y);
                        bz = fmaxf(fmaxf(bz, a0s * u.z), a1s * v.z);
                        bw = fmaxf(fmaxf(bw, a0s * u.w), a1s * v.w);
                    }
                }
                if (e < degn) {
                    float a  = __shfl(a_l, e, 64);
                    int   sn = __shfl(sn_l, e, 64);
                    const float4* srow = (const float4*)(H + (size_t)sn * D);
                    if (q0) {
                        float4 v0 = srow[lane];
                        ax = fmaxf(ax, a * v0.x); ay = fmaxf(ay, a * v0.y);
                        az = fmaxf(az, a * v0.z); aw = fmaxf(aw, a * v0.w);
                    }
                    if (q1) {
                        float4 v1 = srow[64 + lane];
                        bx = fmaxf(bx, a * v1.x); by = fmaxf(by, a * v1.y);
                        bz = fmaxf(bz, a * v1.z); bw = fmaxf(bw, a * v1.w);
                    }
                }
            } else {
                // rare high-degree fallback: recompute scores
                float mm = -INFINITY;
                for (unsigned e = e0 + lane; e < e1; e += 64)
                    mm = fmaxf(mm, lrelu(ps[ssrc[e]] + pdn));
                float m = wrmax(mm);
                float ssum = 0.f;
                for (unsigned e = e0 + lane; e < e1; e += 64)
                    ssum += expf(lrelu(ps[ssrc[e]] + pdn) - m);
                float s = wrsum(ssum), inv = 1.f / s;
                for (unsigned e = e0; e < e1; ++e) {
                    int sn = ssrc[e];
                    float a = expf(lrelu(ps[sn] + pdn) - m) * inv;
                    const float4* srow = (const float4*)(H + (size_t)sn * D);
                    if (q0) {
                        float4 v0 = srow[lane];
                        ax = fmaxf(ax, a * v0.x); ay = fmaxf(ay, a * v0.y);
                        az = fmaxf(az, a * v0.z); aw = fmaxf(aw, a * v0.w);
                    }
                    if (q1) {
                        float4 v1 = srow[64 + lane];
                        bx = fmaxf(bx, a * v1.x); by = fmaxf(by, a * v1.y);
                        bz = fmaxf(bz, a * v1.z); bw = fmaxf(bw, a * v1.w);
                    }
                }
            }
            float et = eta[n], om = 1.f - et;
            hx = et * h0.x + om * ax; hy = et * h0.y + om * ay;
            hz = et * h0.z + om * az; hw = et * h0.w + om * aw;
            gx = et * h1.x + om * bx; gy = et * h1.y + om * by;
            gz = et * h1.z + om * bz; gw = et * h1.w + om * bw;
        }
        // accumulate into register graph sum; flush when graph id changes
        // (gid sorted -> non-decreasing; boundary overlap handled by atomics)
        int g = gid[n];
        if (g != curg) {
            float* row = hg + (size_t)curg * D;
            int c = 4 * lane;
            if (q0) {
                atomicAdd(&row[c + 0], sx); atomicAdd(&row[c + 1], sy);
                atomicAdd(&row[c + 2], sz); atomicAdd(&row[c + 3], sw);
            }
            if (q1) {
                int c1 = 4 * (64 + lane);
                atomicAdd(&row[c1 + 0], tx); atomicAdd(&row[c1 + 1], ty);
                atomicAdd(&row[c1 + 2], tz); atomicAdd(&row[c1 + 3], tw);
            }
            sx = sy = sz = sw = tx = ty = tz = tw = 0.f;
            curg = g;
        }
        sx += hx; sy += hy; sz += hz; sw += hw;
        if (q1) { tx += gx; ty += gy; tz += gz; tw += gw; }
    }
    // final flush
    float* row = hg + (size_t)curg * D;
    int c = 4 * lane;
    if (q0) {
        atomicAdd(&row[c + 0], sx); atomicAdd(&row[c + 1], sy);
        atomicAdd(&row[c + 2], sz); atomicAdd(&row[c + 3], sw);
    }
    if (q1) {
        int c1 = 4 * (64 + lane);
        atomicAdd(&row[c1 + 0], tx); atomicAdd(&row[c1 + 1], ty);
        atomicAdd(&row[c1 + 2], tz); atomicAdd(&row[c1 + 3], tw);
    }
}

// ---- 6. classifier: out[b,c] = sum_d lrelu(hg[b,d]) * Wl[d,c] + bl[c] ----
// One block (64 threads) per graph; lane c owns output class c (C<=64).
// No per-thread arrays -> no scratch.
__global__ __launch_bounds__(64) void k_out(
    const float* __restrict__ hg, const float* __restrict__ Wl,
    const float* __restrict__ bl, float* __restrict__ out,
    int D, int C) {
    int b = blockIdx.x;
    int c = threadIdx.x;
    if (c >= C) return;
    const float* row = hg + (size_t)b * D;
    float acc = 0.f;
    for (int d = 0; d < D; ++d)
        acc += lrelu(row[d]) * Wl[(size_t)d * C + c];
    out[(size_t)b * C + c] = acc + bl[c];
}

// ---------------------------------------------------------------------------
extern "C" void kernel_launch(void* const* d_in, const int* in_sizes, int n_in,
                              void* d_out, int out_size, void* d_ws, size_t ws_size,
                              hipStream_t stream) {
    const float* H   = (const float*)d_in[0];
    const float* eta = (const float*)d_in[1];
    const float* Wa  = (const float*)d_in[2];
    const float* ba  = (const float*)d_in[3];
    const float* Wl  = (const float*)d_in[4];
    const float* bl  = (const float*)d_in[5];
    const int*   src = (const int*)d_in[6];
    const int*   dst = (const int*)d_in[7];
    const int*   gid = (const int*)d_in[8];

    const int N = in_sizes[1];          // eta is [N,1]
    const int D = in_sizes[2] / 2;      // W_attn is [2D,1]
    const int C = in_sizes[5];          // b_lin is [C]
    const int E = in_sizes[6];          // src is [E]
    const int B = out_size / C;         // out is [B,C]

    // workspace layout (all fp32/u32, 4B-aligned), ~7.3 MB total
    char* w = (char*)d_ws;
    float*    ps   = (float*)w;    w += (size_t)N * 4;
    float*    pd   = (float*)w;    w += (size_t)N * 4;
    unsigned* deg  = (unsigned*)w; w += (size_t)N * 4;   // zeroed
    unsigned* cur  = (unsigned*)w; w += (size_t)N * 4;   // zeroed
    float*    hg   = (float*)w;    w += (size_t)B * D * 4; // zeroed
    unsigned* offs = (unsigned*)w; w += (size_t)(N + 1) * 4;
    unsigned* bsum = (unsigned*)w; w += 2048 * 4;
    unsigned* bpre = (unsigned*)w; w += 2048 * 4;
    int*      ssrc = (int*)w;      w += (size_t)E * 4;

    // deg, cur, hg are contiguous -> single memset (re-zeroed every call;
    // harness re-poisons d_ws with 0xAA before each timed launch)
    hipMemsetAsync(deg, 0, (size_t)(2 * N + (size_t)B * D) * 4, stream);

    const int nT = (N + 1023) / 1024;  // scan tiles (needs N <= 2M)

    k_ps_pd<<<dim3((N + 3) / 4), dim3(256), 0, stream>>>(H, Wa, ps, pd, N, D);
    k_hist<<<dim3((E + 255) / 256), dim3(256), 0, stream>>>(dst, deg, E);
    k_scan1<<<dim3(nT), dim3(256), 0, stream>>>(deg, offs, bsum, N);
    k_scan2<<<dim3(1), dim3(256), 0, stream>>>(bsum, bpre, nT);
    k_scan3<<<dim3((N + 255) / 256), dim3(256), 0, stream>>>(offs, bpre, N);
    k_scatter<<<dim3((E + 255) / 256), dim3(256), 0, stream>>>(src, dst, offs, cur, ssrc, E);
    {
        int waves  = (N + KNODES - 1) / KNODES;
        int blocks = (waves + 3) / 4;   // 4 waves per 256-thread block
        k_fused<<<dim3(blocks), dim3(256), 0, stream>>>(H, eta, ps, pd, ba, offs, ssrc, gid, hg, N, D);
    }
    k_out<<<dim3(B), dim3(64), 0, stream>>>(hg, Wl, bl, (float*)d_out, D, C);
}